// Round 2
// baseline (405.028 us; speedup 1.0000x reference)
//
#include <hip/hip_runtime.h>
#include <hip/hip_bf16.h>

// PerforantPR forward on MI355X (gfx950).
// Pipeline: cast->bf16, transpose-cast weights, bf16 MFMA GEMM x2
// (GEMM1 fused bias+leaky+bf16cast; GEMM2 K-split-2 f32 partials),
// row-wise epilogue (bias + BCE + sigmoid + exact radix top-k + softmax
// chain), loss reduce.
//
// B=1024, D_IN=4096, D_HID=4096, D_OUT=2048, K_PR=75, K_SHIFT=51.
// Workspace requirement: 64 MB + 4 KB.

typedef unsigned short u16;
typedef unsigned int u32;
typedef __attribute__((ext_vector_type(4))) float f32x4;
typedef __attribute__((ext_vector_type(8))) short s16x8;

#define GAS __attribute__((address_space(1)))
#define LAS __attribute__((address_space(3)))

__device__ __forceinline__ u16 f2bf(float x) {
  u32 u = __float_as_uint(x);
  u32 r = (u + 0x7FFFu + ((u >> 16) & 1u)) >> 16;  // RNE; no NaN inputs here
  return (u16)r;
}

__device__ __forceinline__ void gld_lds16(const u16* g, u16* l) {
  // async global->LDS, 16B per lane; LDS dest = wave-uniform base + lane*16
  __builtin_amdgcn_global_load_lds((const GAS void*)g, (LAS void*)l, 16, 0, 0);
}

// ---------------------------------------------------------------- casts ----

__global__ void cast_bf16_kernel(const float* __restrict__ in,
                                 u16* __restrict__ out, int n4) {
  int i = blockIdx.x * 256 + threadIdx.x;
  if (i < n4) {
    float4 v = ((const float4*)in)[i];
    u32 p0 = (u32)f2bf(v.x) | ((u32)f2bf(v.y) << 16);
    u32 p1 = (u32)f2bf(v.z) | ((u32)f2bf(v.w) << 16);
    uint2 p; p.x = p0; p.y = p1;
    ((uint2*)out)[i] = p;
  }
}

// in: [R][C] f32 row-major; out: [C][R] bf16 (transposed). R,C multiples of 32.
__global__ __launch_bounds__(256) void tcast_kernel(const float* __restrict__ in,
                                                    u16* __restrict__ out,
                                                    int R, int C) {
  __shared__ float tile[32][33];
  const int cb = blockIdx.x * 32, rb = blockIdx.y * 32;
  const int tx = threadIdx.x, ty = threadIdx.y;  // (32,8)
#pragma unroll
  for (int i = 0; i < 4; i++)
    tile[ty + i * 8][tx] = in[(size_t)(rb + ty + i * 8) * C + cb + tx];
  __syncthreads();
#pragma unroll
  for (int i = 0; i < 4; i++)
    out[(size_t)(cb + ty + i * 8) * R + rb + tx] = f2bf(tile[tx][ty + i * 8]);
}

// ----------------------------------------------------------------- GEMM ----
// C[m][n] = sum_k A[m][k]*BT[n][k]  (A:[M][K] bf16, BT:[N][K] bf16)
// ACT=1: +bias, leaky_relu(0.01), store bf16 (z==0 only).
// ACT=0: raw f32 partial over k in [z*klen, (z+1)*klen) -> out + z*M*N.
// 256 threads = 4 waves (2x2: WM x WN per wave), BK=32.
// Consistent-slot trick: A and B frags both read contiguous 8-k chunks with
// the same (lane,reg)->k map => MFMA pairs identical k-slots => dot correct.

template <int BM, int BN, int WM, int WN, int ACT>
__global__ __launch_bounds__(256, 2) void gemm_bt_kernel(
    const u16* __restrict__ A, const u16* __restrict__ BT,
    const float* __restrict__ bias, void* __restrict__ out,
    int M, int N, int K, int klen) {
  constexpr int BK = 32;
  constexpr int MF = WM / 16, NF = WN / 16;
  constexpr int AI = BM / 16, BI = BN / 16;  // 16-row staging groups
  __shared__ __align__(16) u16 Abuf[BM * BK];
  __shared__ __align__(16) u16 Bbuf[BN * BK];

  const int tid = threadIdx.x;
  const int wid = tid >> 6, lane = tid & 63;
  const int wm = wid >> 1, wn = wid & 1;
  const int n0 = blockIdx.x * BN, m0 = blockIdx.y * BM;
  const int kbase = blockIdx.z * klen;

  f32x4 acc[MF][NF];
#pragma unroll
  for (int f = 0; f < MF; f++)
#pragma unroll
    for (int j = 0; j < NF; j++) acc[f][j] = (f32x4)0.f;

  // staging group i covers rows [i*16, i*16+16): lane l -> row i*16 + (l>>2),
  // 16B k-chunk (l&3); LDS linear dest (l>>2)*64B + (l&3)*16B == l*16B.
  const u16* Ag = A + (size_t)(m0 + (lane >> 2)) * K + kbase + (lane & 3) * 8;
  const u16* Bg = BT + (size_t)(n0 + (lane >> 2)) * K + kbase + (lane & 3) * 8;
  const int fr = lane & 15, fg = lane >> 4;

  for (int kt = 0; kt < klen; kt += BK) {
#pragma unroll
    for (int t = 0; t < AI / 4; t++) {
      const int i = wid + t * 4;
      gld_lds16(Ag + (size_t)i * 16 * K + kt, &Abuf[i * 16 * BK]);
    }
#pragma unroll
    for (int t = 0; t < BI / 4; t++) {
      const int i = wid + t * 4;
      gld_lds16(Bg + (size_t)i * 16 * K + kt, &Bbuf[i * 16 * BK]);
    }
    __syncthreads();  // compiler emits vmcnt(0) drain here

    s16x8 af[MF], bf[NF];
#pragma unroll
    for (int f = 0; f < MF; f++)
      af[f] = *(const s16x8*)&Abuf[(wm * WM + f * 16 + fr) * BK + fg * 8];
#pragma unroll
    for (int j = 0; j < NF; j++)
      bf[j] = *(const s16x8*)&Bbuf[(wn * WN + j * 16 + fr) * BK + fg * 8];
#pragma unroll
    for (int f = 0; f < MF; f++)
#pragma unroll
      for (int j = 0; j < NF; j++)
        acc[f][j] = __builtin_amdgcn_mfma_f32_16x16x32_bf16(af[f], bf[j],
                                                            acc[f][j], 0, 0, 0);
    __syncthreads();
  }

  // epilogue; C/D layout: col=lane&15, row=(lane>>4)*4+reg  [m89-verified]
#pragma unroll
  for (int j = 0; j < NF; j++) {
    const int col = n0 + wn * WN + j * 16 + fr;
    const float bv = ACT ? bias[col] : 0.f;
#pragma unroll
    for (int f = 0; f < MF; f++) {
#pragma unroll
      for (int q = 0; q < 4; q++) {
        const int row = m0 + wm * WM + f * 16 + fg * 4 + q;
        if (ACT) {
          float v = acc[f][j][q] + bv;
          v = (v > 0.f) ? v : 0.01f * v;  // jax.nn.leaky_relu default slope
          ((u16*)out)[(size_t)row * N + col] = f2bf(v);
        } else {
          float* o = (float*)out + (size_t)blockIdx.z * M * N;
          o[(size_t)row * N + col] = acc[f][j][q];
        }
      }
    }
  }
}

// ------------------------------------------------------------- reduces -----

__device__ __forceinline__ float bred_sum_f(float v, volatile float* s, int tid) {
  __syncthreads();
#pragma unroll
  for (int o = 32; o; o >>= 1) v += __shfl_down(v, o, 64);
  if ((tid & 63) == 0) s[tid >> 6] = v;
  __syncthreads();
  return s[0] + s[1] + s[2] + s[3];
}
__device__ __forceinline__ float bred_max_f(float v, volatile float* s, int tid) {
  __syncthreads();
#pragma unroll
  for (int o = 32; o; o >>= 1) v = fmaxf(v, __shfl_down(v, o, 64));
  if ((tid & 63) == 0) s[tid >> 6] = v;
  __syncthreads();
  return fmaxf(fmaxf(s[0], s[1]), fmaxf(s[2], s[3]));
}
__device__ __forceinline__ u32 bred_sum_u(u32 v, volatile u32* s, int tid) {
  __syncthreads();
#pragma unroll
  for (int o = 32; o; o >>= 1) v += (u32)__shfl_down((int)v, o, 64);
  if ((tid & 63) == 0) s[tid >> 6] = v;
  __syncthreads();
  return s[0] + s[1] + s[2] + s[3];
}

// Exact k-th largest of 2048 positive floats (bit-pattern radix select, 4x8bit)
__device__ float radix_kth_desc(u32 k, const u32* yb, u32* hist, u32* bc, int tid) {
  u32 prefix = 0, pmask = 0, krem = k;
  for (int pass = 0; pass < 4; pass++) {
    const int sh = 24 - 8 * pass;
    hist[tid] = 0;
    __syncthreads();
#pragma unroll
    for (int j = 0; j < 8; j++) {
      u32 v = yb[tid * 8 + j];
      if ((v & pmask) == prefix) atomicAdd(&hist[(v >> sh) & 0xFFu], 1u);
    }
    __syncthreads();
    // suffix sum: hist[b] = count of matching values with digit >= b
    for (int off = 1; off < 256; off <<= 1) {
      u32 add = (tid + off < 256) ? hist[tid + off] : 0u;
      __syncthreads();
      hist[tid] += add;
      __syncthreads();
    }
    u32 Sb = hist[tid];
    u32 Sn = (tid < 255) ? hist[tid + 1] : 0u;
    if (Sb >= krem && (tid == 255 || Sn < krem)) { bc[0] = (u32)tid; bc[1] = krem - Sn; }
    __syncthreads();
    prefix |= bc[0] << sh;
    pmask |= 0xFFu << sh;
    krem = bc[1];
    __syncthreads();
  }
  return __uint_as_float(prefix);
}

// ------------------------------------------------------------ epilogue -----
// One block (256 thr) per row. logits = partA + partB + b_dec -> BCE partial,
// pr_out, z_cue_in, z_cue. Monotonicity: top-51-of-pr == top-51-of-y, and
// min(top51 pr) = GAIN*exp(c*t51 - M)/Z, so the 51-select needs only t51.

__global__ __launch_bounds__(256) void epilogue_kernel(
    const float* __restrict__ pA, const float* __restrict__ pB,
    const float* __restrict__ b_dec, const float* __restrict__ targets,
    float* __restrict__ out, float* __restrict__ lossp) {
  __shared__ u32 yb[2048];
  __shared__ u32 hist[256];
  __shared__ u32 bc[2];
  __shared__ unsigned char selm[2048];
  __shared__ float sf[8];
  __shared__ u32 su[8];

  const int r = blockIdx.x, tid = threadIdx.x;

  float l[8], tg[8], y[8];
  {
    const float4* a = (const float4*)(pA + (size_t)r * 2048 + tid * 8);
    const float4* b = (const float4*)(pB + (size_t)r * 2048 + tid * 8);
    const float4* c = (const float4*)(b_dec + tid * 8);
    float4 a0 = a[0], a1 = a[1], b0 = b[0], b1 = b[1], c0 = c[0], c1 = c[1];
    l[0] = a0.x + b0.x + c0.x; l[1] = a0.y + b0.y + c0.y;
    l[2] = a0.z + b0.z + c0.z; l[3] = a0.w + b0.w + c0.w;
    l[4] = a1.x + b1.x + c1.x; l[5] = a1.y + b1.y + c1.y;
    l[6] = a1.z + b1.z + c1.z; l[7] = a1.w + b1.w + c1.w;
  }
  {
    const float4* p = (const float4*)(targets + (size_t)r * 2048 + tid * 8);
    float4 a = p[0], b = p[1];
    tg[0] = a.x; tg[1] = a.y; tg[2] = a.z; tg[3] = a.w;
    tg[4] = b.x; tg[5] = b.y; tg[6] = b.z; tg[7] = b.w;
  }

  float bce = 0.f, ymax = 0.f;
#pragma unroll
  for (int j = 0; j < 8; j++) {
    float li = l[j];
    bce += fmaxf(li, 0.f) - li * tg[j] + log1pf(expf(-fabsf(li)));
    float yi = 1.f / (1.f + expf(-li));  // in (0,1): clip is a no-op
    y[j] = yi;
    yb[tid * 8 + j] = __float_as_uint(yi);
    ymax = fmaxf(ymax, yi);
  }
  float bsum = bred_sum_f(bce, sf, tid);
  if (tid == 0) lossp[r] = bsum;
  ymax = bred_max_f(ymax, sf, tid);
  // (reduce barriers also make yb visible before radix reads)

  const float t75 = radix_kth_desc(75, yb, hist, bc, tid);

  u32 cgt = 0, ceq = 0; float sgt = 0.f;
#pragma unroll
  for (int j = 0; j < 8; j++) {
    if (y[j] > t75)       { cgt++; sgt += y[j]; }
    else if (y[j] == t75) { ceq++; }
  }
  const u32 G = bred_sum_u(cgt, su, tid);
  const u32 E = bred_sum_u(ceq, su, tid);
  const float SG = bred_sum_f(sgt, sf, tid);
  const u32 need = 75 - G;                 // 1 <= need <= E always
  const float ysum = SG + (float)need * t75;

  const float t51 = radix_kth_desc(51, yb, hist, bc, tid);

  // top-75 mask with jax tie-break (lowest index first among equals)
#pragma unroll
  for (int j = 0; j < 8; j++)
    selm[tid * 8 + j] = (y[j] > t75) ? (unsigned char)1
                       : ((y[j] == t75) ? (unsigned char)2 : (unsigned char)0);
  __syncthreads();
  const bool rare = (need != E);           // uniform (from broadcast reduces)
  if (rare && tid == 0) {
    u32 left = need;
    for (int e = 0; e < 2048; e++)
      if (selm[e] == 2) { selm[e] = left ? 1 : 0; if (left) left--; }
  }
  __syncthreads();

  const float c = 1.f / ysum + 1e-13f;     // (1/y_sum + EPS) * SUM_NORM
  const float Mv = c * ymax;               // softmax max (top-1 is selected)
  float ex[8]; float zs = 0.f;
#pragma unroll
  for (int j = 0; j < 8; j++) {
    unsigned char s = selm[tid * 8 + j];
    bool sel = rare ? (s == 1) : (s != 0);
    float v = sel ? c * y[j] : 0.f;
    float e = expf(v - Mv);
    ex[j] = e; zs += e;
  }
  const float Z = bred_sum_f(zs, sf, tid);
  const float gZ = 2.f / Z;                                // GAIN/Z
  const float shift = 1.f - 2.f * (expf(c * t51 - Mv) * gZ);  // 1-2*pr(51st)

  float* pr_o = out + 1;
  float* zi_o = out + 1 + 2097152;
  float* zc_o = out + 1 + 4194304;
#pragma unroll
  for (int j = 0; j < 8; j++) {
    size_t o = (size_t)r * 2048 + tid * 8 + j;
    float pr = ex[j] * gZ;
    pr_o[o] = pr;
    float zi = 2.f * pr - 1.f;
    zi_o[o] = zi;
    zc_o[o] = zi + shift;
  }
}

__global__ void loss_reduce_kernel(const float* __restrict__ lp,
                                   float* __restrict__ out) {
  __shared__ float sf[8];
  const int tid = threadIdx.x;
  float s = 0.f;
  for (int i = tid; i < 1024; i += 256) s += lp[i];
  float tot = bred_sum_f(s, sf, tid);
  if (tid == 0) out[0] = tot * (1.f / (1024.f * 2048.f));
}

// -------------------------------------------------------------- launch -----

extern "C" void kernel_launch(void* const* d_in, const int* in_sizes, int n_in,
                              void* d_out, int out_size, void* d_ws, size_t ws_size,
                              hipStream_t stream) {
  (void)in_sizes; (void)n_in; (void)out_size; (void)ws_size;
  const float* inputs  = (const float*)d_in[0];  // [1024][4096]
  const float* targets = (const float*)d_in[1];  // [1024][2048]
  const float* w_enc   = (const float*)d_in[2];  // [4096][4096]
  const float* b_enc   = (const float*)d_in[3];  // [4096]
  const float* w_dec   = (const float*)d_in[4];  // [4096][2048]
  const float* b_dec   = (const float*)d_in[5];  // [2048]
  float* out = (float*)d_out;

  char* ws = (char*)d_ws;
  u16* A16    = (u16*)ws;                        //  8 MB  [0, 8M)
  u16* W1T    = (u16*)(ws + (8u << 20));         // 32 MB  [8M, 40M)
  u16* W2T    = (u16*)(ws + (40u << 20));        // 16 MB  [40M, 56M)
  u16* H16    = (u16*)(ws + (56u << 20));        //  8 MB  [56M, 64M)
  float* lossp = (float*)(ws + (64u << 20));     //  4 KB
  // logits partials overlay W1T (dead after GEMM1): 2 x 8 MB
  float* lgts = (float*)(ws + (8u << 20));

  cast_bf16_kernel<<<4096, 256, 0, stream>>>(inputs, A16, 1024 * 4096 / 4);
  tcast_kernel<<<dim3(128, 128), dim3(32, 8), 0, stream>>>(w_enc, W1T, 4096, 4096);
  tcast_kernel<<<dim3(64, 128), dim3(32, 8), 0, stream>>>(w_dec, W2T, 4096, 2048);

  // hidden = leaky_relu(A @ W1 + b_enc) -> bf16   (512 blocks, 2/CU)
  gemm_bt_kernel<128, 64, 64, 32, 1><<<dim3(64, 8), 256, 0, stream>>>(
      A16, W1T, b_enc, (void*)H16, 1024, 4096, 4096, 4096);
  // logits partials = hidden @ W2 (K-split 2)     (512 blocks, 2/CU)
  gemm_bt_kernel<128, 64, 64, 32, 0><<<dim3(32, 8, 2), 256, 0, stream>>>(
      H16, W2T, nullptr, (void*)lgts, 1024, 2048, 4096, 2048);

  epilogue_kernel<<<1024, 256, 0, stream>>>(lgts, lgts + (size_t)1024 * 2048,
                                            b_dec, targets, out, lossp);
  loss_reduce_kernel<<<1, 256, 0, stream>>>(lossp, out);
}

// Round 5
// 320.526 us; speedup vs baseline: 1.2636x; 1.2636x over previous
//
#include <hip/hip_runtime.h>
#include <hip/hip_bf16.h>

// PerforantPR forward on MI355X (gfx950).
// R5 == R4 resubmission (R4 never ran: GPU acquisition timeout).
// Single 64MB-workspace path. GEMMs: 2-phase pipelined 128x128/BK=64
// (double-buffered LDS, stage-next-before-compute, one barrier per K-step).
// GEMM2 K-split-4 f32 partials (overlaying dead W1T), summed in the
// wave-local epilogue (0 barriers, 0 LDS, exact dual bit-search top-k).
//
// B=1024, D_IN=4096, D_HID=4096, D_OUT=2048, K_PR=75, K_SHIFT=51.

typedef unsigned short u16;
typedef unsigned int u32;
typedef __attribute__((ext_vector_type(4))) float f32x4;
typedef __attribute__((ext_vector_type(8))) short s16x8;

#define GAS __attribute__((address_space(1)))
#define LAS __attribute__((address_space(3)))

__device__ __forceinline__ u16 f2bf(float x) {
  u32 u = __float_as_uint(x);
  u32 r = (u + 0x7FFFu + ((u >> 16) & 1u)) >> 16;  // RNE; no NaN inputs here
  return (u16)r;
}

__device__ __forceinline__ void gld_lds16(const u16* g, u16* l) {
  // async global->LDS, 16B per lane; LDS dest = wave-uniform base + lane*16
  __builtin_amdgcn_global_load_lds((const GAS void*)g, (LAS void*)l, 16, 0, 0);
}

// ---------------------------------------------------------------- casts ----

__global__ void cast_bf16_kernel(const float* __restrict__ in,
                                 u16* __restrict__ out, int n4) {
  int i = blockIdx.x * 256 + threadIdx.x;
  if (i < n4) {
    float4 v = ((const float4*)in)[i];
    u32 p0 = (u32)f2bf(v.x) | ((u32)f2bf(v.y) << 16);
    u32 p1 = (u32)f2bf(v.z) | ((u32)f2bf(v.w) << 16);
    uint2 p; p.x = p0; p.y = p1;
    ((uint2*)out)[i] = p;
  }
}

// in: [R][C] f32 row-major; out: [C][R] bf16 (transposed). R,C multiples of 32.
__global__ __launch_bounds__(256) void tcast_kernel(const float* __restrict__ in,
                                                    u16* __restrict__ out,
                                                    int R, int C) {
  __shared__ float tile[32][33];
  const int cb = blockIdx.x * 32, rb = blockIdx.y * 32;
  const int tx = threadIdx.x, ty = threadIdx.y;  // (32,8)
#pragma unroll
  for (int i = 0; i < 4; i++)
    tile[ty + i * 8][tx] = in[(size_t)(rb + ty + i * 8) * C + cb + tx];
  __syncthreads();
#pragma unroll
  for (int i = 0; i < 4; i++)
    out[(size_t)(cb + ty + i * 8) * R + rb + tx] = f2bf(tile[tx][ty + i * 8]);
}

// ----------------------------------------------------------------- GEMM ----
// 2-phase pipelined: C[m][n] = sum_k A[m][k]*BT[n][k], A:[M][K], BT:[N][K].
// 128x128 tile, BK=64, 4 waves (2x2) of 64x64, double-buffered LDS (64 KB).
// Per K-step: STAGE next tile (8 gld_lds16/wave) -> ds_read+32 MFMA on
// current -> one __syncthreads() (drains vmcnt for the staged buffer AND
// fences reads of the current buffer before it is overwritten next iter).
// ACT=1: +bias, leaky_relu(0.01), bf16 out (z==0 only).
// ACT=0: raw f32 partial over k in [z*klen,(z+1)*klen) -> out + z*M*N.
// Consistent-slot trick: A and B fragments use the same (lane,reg)->k map
// (row=lane&15, 8-elem chunk = (kk,lane>>4)) => MFMA pairs identical k-slots.

template <int ACT>
__global__ __launch_bounds__(256, 2) void gemm2ph_kernel(
    const u16* __restrict__ A, const u16* __restrict__ BT,
    const float* __restrict__ bias, void* __restrict__ out,
    int M, int N, int K, int klen) {
  constexpr int BM = 128, BN = 128, BK = 64;
  constexpr int MF = 4, NF = 4;  // 64x64 per wave
  constexpr int BUF = BM * BK + BN * BK;  // elements per buffer
  __shared__ __align__(16) u16 smem[2 * BUF];  // 64 KB

  const int tid = threadIdx.x;
  const int wid = tid >> 6, lane = tid & 63;
  const int wm = wid >> 1, wn = wid & 1;
  const int n0 = blockIdx.x * BN, m0 = blockIdx.y * BM;
  const int kbase = blockIdx.z * klen;

  f32x4 acc[MF][NF];
#pragma unroll
  for (int f = 0; f < MF; f++)
#pragma unroll
    for (int j = 0; j < NF; j++) acc[f][j] = (f32x4)0.f;

  // staging inst i covers 8 rows [i*8, i*8+8): lane l -> row i*8 + (l>>3),
  // 16B chunk (l&7); LDS linear dest (l>>3)*128B + (l&7)*16B == l*16B.
  const u16* Ag = A + (size_t)(m0 + (lane >> 3)) * K + kbase + (lane & 7) * 8;
  const u16* Bg = BT + (size_t)(n0 + (lane >> 3)) * K + kbase + (lane & 7) * 8;
  const int fr = lane & 15, fg = lane >> 4;
  const int NT = klen / BK;

  auto stage = [&](int b, int koff) {
    u16* Al = smem + b * BUF;
    u16* Bl = Al + BM * BK;
#pragma unroll
    for (int t2 = 0; t2 < 4; t2++) {
      const int i = wid * 4 + t2;  // 16 insts for A, 16 for B, 4+4 per wave
      gld_lds16(Ag + (size_t)i * 8 * K + koff, Al + i * 512);
      gld_lds16(Bg + (size_t)i * 8 * K + koff, Bl + i * 512);
    }
  };

  stage(0, 0);
  __syncthreads();
  int cur = 0;
  for (int t = 0; t < NT; t++) {
    if (t + 1 < NT) stage(cur ^ 1, (t + 1) * BK);  // issue-early prefetch

    const u16* Ab = smem + cur * BUF;
    const u16* Bb = Ab + BM * BK;
    s16x8 af[MF][2], bf[NF][2];
#pragma unroll
    for (int f = 0; f < MF; f++)
#pragma unroll
      for (int kk = 0; kk < 2; kk++)
        af[f][kk] = *(const s16x8*)&Ab[(wm * 64 + f * 16 + fr) * BK + kk * 32 + fg * 8];
#pragma unroll
    for (int j = 0; j < NF; j++)
#pragma unroll
      for (int kk = 0; kk < 2; kk++)
        bf[j][kk] = *(const s16x8*)&Bb[(wn * 64 + j * 16 + fr) * BK + kk * 32 + fg * 8];
#pragma unroll
    for (int kk = 0; kk < 2; kk++)
#pragma unroll
      for (int f = 0; f < MF; f++)
#pragma unroll
        for (int j = 0; j < NF; j++)
          acc[f][j] = __builtin_amdgcn_mfma_f32_16x16x32_bf16(
              af[f][kk], bf[j][kk], acc[f][j], 0, 0, 0);

    __syncthreads();  // drains staged loads; fences reads before overwrite
    cur ^= 1;
  }

  // C-write; C/D layout: col=lane&15, row=(lane>>4)*4+reg  [m89-verified,
  // end-to-end validated by R2's passing absmax]
#pragma unroll
  for (int j = 0; j < NF; j++) {
    const int col = n0 + wn * 64 + j * 16 + fr;
    const float bv = ACT ? bias[col] : 0.f;
#pragma unroll
    for (int f = 0; f < MF; f++) {
#pragma unroll
      for (int q = 0; q < 4; q++) {
        const int row = m0 + wm * 64 + f * 16 + fg * 4 + q;
        if (ACT) {
          float v = acc[f][j][q] + bv;
          v = (v > 0.f) ? v : 0.01f * v;  // jax.nn.leaky_relu default slope
          ((u16*)out)[(size_t)row * N + col] = f2bf(v);
        } else {
          float* o = (float*)out + (size_t)blockIdx.z * M * N;
          o[(size_t)row * N + col] = acc[f][j][q];
        }
      }
    }
  }
}

// ----------------------------------------------------- wave reductions -----

__device__ __forceinline__ float wred_sum(float v) {
#pragma unroll
  for (int o = 32; o; o >>= 1) v += __shfl_xor(v, o, 64);
  return v;
}
__device__ __forceinline__ float wred_max(float v) {
#pragma unroll
  for (int o = 32; o; o >>= 1) v = fmaxf(v, __shfl_xor(v, o, 64));
  return v;
}
__device__ __forceinline__ u32 wred_sumu(u32 v) {
#pragma unroll
  for (int o = 32; o; o >>= 1) v += (u32)__shfl_xor((int)v, o, 64);
  return v;
}

// ------------------------------------------------------------ epilogue -----
// One WAVE per row (4 waves/block, 256 blocks = 1024 rows). Zero barriers,
// zero LDS. Lane l owns columns [l*32, l*32+32).
// logits = p0+p1+p2+p3 + b_dec. Exact k-th largest via bit-serial binary
// search on positive-float bit patterns (monotone as u32):
//   T = max{T : count(y >= T) >= k}  ==  k-th largest value.
// Both thresholds (k=75, k=51) searched simultaneously, counts packed 16+16.
// Monotonicity: top-51-of-pr == top-51-of-y; pr51 = GAIN*exp(c*t51-Mv)/Z
// (holds under ties: tied-at-boundary selected entries share pr value).

__global__ __launch_bounds__(256) void epilogue_wave_kernel(
    const float* __restrict__ p0, const float* __restrict__ p1,
    const float* __restrict__ p2, const float* __restrict__ p3,
    const float* __restrict__ b_dec, const float* __restrict__ targets,
    float* __restrict__ out, float* __restrict__ lossp) {
  const int tid = threadIdx.x;
  const int widx = tid >> 6, lane = tid & 63;
  const int r = blockIdx.x * 4 + widx;
  const size_t base = (size_t)r * 2048 + lane * 32;

  u32 u[32];
  float bce = 0.f, ymax = 0.f;
#pragma unroll
  for (int g = 0; g < 8; g++) {
    float4 a = *(const float4*)(p0 + base + g * 4);
    float4 b = *(const float4*)(p1 + base + g * 4);
    float4 d = *(const float4*)(p2 + base + g * 4);
    float4 e = *(const float4*)(p3 + base + g * 4);
    float4 c4 = *(const float4*)(b_dec + lane * 32 + g * 4);
    float4 t4 = *(const float4*)(targets + base + g * 4);
    float lv[4] = {a.x + b.x + d.x + e.x + c4.x, a.y + b.y + d.y + e.y + c4.y,
                   a.z + b.z + d.z + e.z + c4.z, a.w + b.w + d.w + e.w + c4.w};
    float tv[4] = {t4.x, t4.y, t4.z, t4.w};
#pragma unroll
    for (int j = 0; j < 4; j++) {
      float li = lv[j];
      bce += fmaxf(li, 0.f) - li * tv[j] + log1pf(expf(-fabsf(li)));
      float yi = 1.f / (1.f + expf(-li));  // in (0,1): clip is a no-op
      u[g * 4 + j] = __float_as_uint(yi);
      ymax = fmaxf(ymax, yi);
    }
  }
  bce = wred_sum(bce);
  if (lane == 0) lossp[r] = bce;
  ymax = wred_max(ymax);

  // dual binary search: y < 1 => bits 31,30 are 0; search bits 29..0
  u32 T75 = 0, T51 = 0;
  for (int b = 29; b >= 0; b--) {
    const u32 c75 = T75 | (1u << b), c51 = T51 | (1u << b);
    u32 cnt = 0;
#pragma unroll
    for (int i = 0; i < 32; i++) {
      cnt += (u[i] >= c75) ? 1u : 0u;
      cnt += (u[i] >= c51) ? 0x10000u : 0u;
    }
    cnt = wred_sumu(cnt);
    if ((cnt & 0xFFFFu) >= 75u) T75 = c75;
    if ((cnt >> 16) >= 51u) T51 = c51;
  }

  // counts & sum over strictly-greater; eq count for tie handling
  u32 cc = 0; float sgt = 0.f;
#pragma unroll
  for (int i = 0; i < 32; i++) {
    if (u[i] > T75)       { cc += 1u; sgt += __uint_as_float(u[i]); }
    else if (u[i] == T75) { cc += 0x10000u; }
  }
  cc = wred_sumu(cc);
  sgt = wred_sum(sgt);
  const u32 G = cc & 0xFFFFu, E = cc >> 16;
  const u32 need = 75u - G;  // 1 <= need <= E
  const float t75f = __uint_as_float(T75);
  const float ysum = sgt + (float)need * t75f;

  // selection mask (bit i = col lane*32+i selected)
  u32 selmask = 0;
#pragma unroll
  for (int i = 0; i < 32; i++)
    if (u[i] >= T75) selmask |= (1u << i);
  if (need != E) {  // rare: jax tie-break keeps lowest global indices
    u32 eqm = 0;
#pragma unroll
    for (int i = 0; i < 32; i++)
      if (u[i] == T75) eqm |= (1u << i);
    u32 eqc = __popc(eqm);
    u32 pre = eqc;  // inclusive scan across lanes -> exclusive
#pragma unroll
    for (int o = 1; o < 64; o <<= 1) {
      u32 t = (u32)__shfl_up((int)pre, o, 64);
      if (lane >= o) pre += t;
    }
    pre -= eqc;
    u32 m = eqm, rank = pre;
    while (m) {
      u32 i = (u32)__ffs(m) - 1u;
      m &= m - 1u;
      if (rank >= need) selmask &= ~(1u << i);
      rank++;
    }
  }

  // softmax chain: y_masked * (1/sum + eps), softmax (stable), gain
  const float c = 1.f / ysum + 1e-13f;
  const float Mv = c * ymax;  // max of masked-scaled row (top-1 is selected)
  float zs = 0.f;
#pragma unroll
  for (int i = 0; i < 32; i++) {
    float yi = __uint_as_float(u[i]);
    float v = ((selmask >> i) & 1u) ? c * yi : 0.f;
    float e = expf(v - Mv);
    zs += e;
    u[i] = __float_as_uint(e);  // reuse register file
  }
  const float Z = wred_sum(zs);
  const float gZ = 2.f / Z;  // GAIN / Z
  const float shift = 1.f - 2.f * (expf(c * __uint_as_float(T51) - Mv) * gZ);

  float* pr_o = out + 1;
  float* zi_o = out + 1 + 2097152;
  float* zc_o = out + 1 + 4194304;
  // lane writes its own 128B line per array (32 scalar dwords, full line)
#pragma unroll
  for (int i = 0; i < 32; i++) {
    float pr = __uint_as_float(u[i]) * gZ;
    float zi = 2.f * pr - 1.f;
    pr_o[base + i] = pr;
    zi_o[base + i] = zi;
    zc_o[base + i] = zi + shift;
  }
}

__global__ void loss_reduce_kernel(const float* __restrict__ lp,
                                   float* __restrict__ out) {
  const int tid = threadIdx.x;
  float s = 0.f;
  for (int i = tid; i < 1024; i += 256) s += lp[i];
  __shared__ float sf[4];
  float v = s;
#pragma unroll
  for (int o = 32; o; o >>= 1) v += __shfl_down(v, o, 64);
  if ((tid & 63) == 0) sf[tid >> 6] = v;
  __syncthreads();
  if (tid == 0) out[0] = (sf[0] + sf[1] + sf[2] + sf[3]) * (1.f / (1024.f * 2048.f));
}

// -------------------------------------------------------------- launch -----

extern "C" void kernel_launch(void* const* d_in, const int* in_sizes, int n_in,
                              void* d_out, int out_size, void* d_ws, size_t ws_size,
                              hipStream_t stream) {
  (void)in_sizes; (void)n_in; (void)out_size; (void)ws_size;
  const float* inputs  = (const float*)d_in[0];  // [1024][4096]
  const float* targets = (const float*)d_in[1];  // [1024][2048]
  const float* w_enc   = (const float*)d_in[2];  // [4096][4096]
  const float* b_enc   = (const float*)d_in[3];  // [4096]
  const float* w_dec   = (const float*)d_in[4];  // [4096][2048]
  const float* b_dec   = (const float*)d_in[5];  // [2048]
  float* out = (float*)d_out;

  // 64 MB workspace layout (exactly R2's proven footprint):
  char* ws = (char*)d_ws;
  u16* A16 = (u16*)ws;                      //  8 MB  [0, 8M)   dead post-GEMM1
  u16* W1T = (u16*)(ws + (8u << 20));       // 32 MB  [8M, 40M) dead post-GEMM1
  u16* W2T = (u16*)(ws + (40u << 20));      // 16 MB  [40M,56M)
  u16* H16 = (u16*)(ws + (56u << 20));      //  8 MB  [56M,64M)
  float* lgts  = (float*)(ws + (8u << 20)); // 4x8 MB overlays dead W1T
  float* lossp = (float*)ws;                //  4 KB  overlays dead A16

  cast_bf16_kernel<<<4096, 256, 0, stream>>>(inputs, A16, 1024 * 4096 / 4);
  tcast_kernel<<<dim3(128, 128), dim3(32, 8), 0, stream>>>(w_enc, W1T, 4096, 4096);
  tcast_kernel<<<dim3(64, 128), dim3(32, 8), 0, stream>>>(w_dec, W2T, 4096, 2048);

  // hidden = leaky_relu(A @ W1 + b_enc) -> bf16   (grid 256, 1 block/CU)
  gemm2ph_kernel<1><<<dim3(32, 8), 256, 0, stream>>>(
      A16, W1T, b_enc, (void*)H16, 1024, 4096, 4096, 4096);
  // logits partials = hidden @ W2, K-split 4      (grid 512, 2 blocks/CU)
  gemm2ph_kernel<0><<<dim3(16, 8, 4), 256, 0, stream>>>(
      H16, W2T, nullptr, (void*)lgts, 1024, 2048, 4096, 1024);

  const float* q0 = lgts;
  const float* q1 = lgts + (size_t)2 * 1024 * 1024;
  const float* q2 = lgts + (size_t)4 * 1024 * 1024;
  const float* q3 = lgts + (size_t)6 * 1024 * 1024;
  epilogue_wave_kernel<<<256, 256, 0, stream>>>(q0, q1, q2, q3, b_dec,
                                                targets, out, lossp);
  loss_reduce_kernel<<<1, 256, 0, stream>>>(lossp, out);
}

// Round 6
// 289.042 us; speedup vs baseline: 1.4013x; 1.1089x over previous
//
#include <hip/hip_runtime.h>
#include <hip/hip_bf16.h>

// PerforantPR forward on MI355X (gfx950).
// R6: epilogue ownership interleaved (reg r=g*4+j, lane l -> col g*256+l*4+j)
// so every global load/store instruction is a contiguous 1KB/wave span
// (kills the 2.3x memory amplification seen in R5 counters); rare tie-break
// re-derived for (g,l,j) order via ballot-rank. Prep kernels fused into one
// dispatch. GEMMs unchanged from R5 (2-phase pipelined 128x128/BK=64).
//
// B=1024, D_IN=4096, D_HID=4096, D_OUT=2048, K_PR=75, K_SHIFT=51.

typedef unsigned short u16;
typedef unsigned int u32;
typedef unsigned long long u64;
typedef __attribute__((ext_vector_type(4))) float f32x4;
typedef __attribute__((ext_vector_type(8))) short s16x8;

#define GAS __attribute__((address_space(1)))
#define LAS __attribute__((address_space(3)))

__device__ __forceinline__ u16 f2bf(float x) {
  u32 u = __float_as_uint(x);
  u32 r = (u + 0x7FFFu + ((u >> 16) & 1u)) >> 16;  // RNE; no NaN inputs here
  return (u16)r;
}

__device__ __forceinline__ void gld_lds16(const u16* g, u16* l) {
  // async global->LDS, 16B per lane; LDS dest = wave-uniform base + lane*16
  __builtin_amdgcn_global_load_lds((const GAS void*)g, (LAS void*)l, 16, 0, 0);
}

// ------------------------------------------------------------ fused prep ---
// blocks [0,4096): cast inputs f32->bf16 (uint2 stores)
// blocks [4096,20480): transpose-cast w_enc [4096][4096] -> W1T
// blocks [20480,28672): transpose-cast w_dec [4096][2048] -> W2T

__device__ __forceinline__ void tcast_body(const float* __restrict__ in,
                                           u16* __restrict__ out, int R, int C,
                                           int bx, int by, int tid) {
  __shared__ float tile[32][33];
  const int cb = bx * 32, rb = by * 32;
  const int tx = tid & 31, ty = tid >> 5;  // 32 x 8
#pragma unroll
  for (int i = 0; i < 4; i++)
    tile[ty + i * 8][tx] = in[(size_t)(rb + ty + i * 8) * C + cb + tx];
  __syncthreads();
#pragma unroll
  for (int i = 0; i < 4; i++)
    out[(size_t)(cb + ty + i * 8) * R + rb + tx] = f2bf(tile[tx][ty + i * 8]);
}

__global__ __launch_bounds__(256) void prep_kernel(
    const float* __restrict__ inputs, const float* __restrict__ w_enc,
    const float* __restrict__ w_dec, u16* __restrict__ A16,
    u16* __restrict__ W1T, u16* __restrict__ W2T) {
  const int bid = blockIdx.x, tid = threadIdx.x;
  if (bid < 4096) {
    const int i = bid * 256 + tid;  // n4 = 1024*4096/4 = exactly 4096*256
    float4 v = ((const float4*)inputs)[i];
    uint2 p;
    p.x = (u32)f2bf(v.x) | ((u32)f2bf(v.y) << 16);
    p.y = (u32)f2bf(v.z) | ((u32)f2bf(v.w) << 16);
    ((uint2*)A16)[i] = p;
  } else if (bid < 20480) {
    const int idx = bid - 4096;  // 128 x 128 tiles
    tcast_body(w_enc, W1T, 4096, 4096, idx & 127, idx >> 7, tid);
  } else {
    const int idx = bid - 20480;  // 64 x 128 tiles
    tcast_body(w_dec, W2T, 4096, 2048, idx & 63, idx >> 6, tid);
  }
}

// ----------------------------------------------------------------- GEMM ----
// 2-phase pipelined: C[m][n] = sum_k A[m][k]*BT[n][k], A:[M][K], BT:[N][K].
// 128x128 tile, BK=64, 4 waves (2x2) of 64x64, double-buffered LDS (64 KB).
// Per K-step: STAGE next tile (8 gld_lds16/wave) -> ds_read+32 MFMA on
// current -> one __syncthreads() (drains vmcnt for the staged buffer AND
// fences reads of the current buffer before it is overwritten next iter).
// ACT=1: +bias, leaky_relu(0.01), bf16 out (z==0 only).
// ACT=0: raw f32 partial over k in [z*klen,(z+1)*klen) -> out + z*M*N.
// Consistent-slot trick: A and B fragments use the same (lane,reg)->k map
// (row=lane&15, 8-elem chunk = (kk,lane>>4)) => MFMA pairs identical k-slots.

template <int ACT>
__global__ __launch_bounds__(256, 2) void gemm2ph_kernel(
    const u16* __restrict__ A, const u16* __restrict__ BT,
    const float* __restrict__ bias, void* __restrict__ out,
    int M, int N, int K, int klen) {
  constexpr int BM = 128, BN = 128, BK = 64;
  constexpr int MF = 4, NF = 4;  // 64x64 per wave
  constexpr int BUF = BM * BK + BN * BK;  // elements per buffer
  __shared__ __align__(16) u16 smem[2 * BUF];  // 64 KB

  const int tid = threadIdx.x;
  const int wid = tid >> 6, lane = tid & 63;
  const int wm = wid >> 1, wn = wid & 1;
  const int n0 = blockIdx.x * BN, m0 = blockIdx.y * BM;
  const int kbase = blockIdx.z * klen;

  f32x4 acc[MF][NF];
#pragma unroll
  for (int f = 0; f < MF; f++)
#pragma unroll
    for (int j = 0; j < NF; j++) acc[f][j] = (f32x4)0.f;

  // staging inst i covers 8 rows [i*8, i*8+8): lane l -> row i*8 + (l>>3),
  // 16B chunk (l&7); LDS linear dest (l>>3)*128B + (l&7)*16B == l*16B.
  const u16* Ag = A + (size_t)(m0 + (lane >> 3)) * K + kbase + (lane & 7) * 8;
  const u16* Bg = BT + (size_t)(n0 + (lane >> 3)) * K + kbase + (lane & 7) * 8;
  const int fr = lane & 15, fg = lane >> 4;
  const int NT = klen / BK;

  auto stage = [&](int b, int koff) {
    u16* Al = smem + b * BUF;
    u16* Bl = Al + BM * BK;
#pragma unroll
    for (int t2 = 0; t2 < 4; t2++) {
      const int i = wid * 4 + t2;  // 16 insts for A, 16 for B, 4+4 per wave
      gld_lds16(Ag + (size_t)i * 8 * K + koff, Al + i * 512);
      gld_lds16(Bg + (size_t)i * 8 * K + koff, Bl + i * 512);
    }
  };

  stage(0, 0);
  __syncthreads();
  int cur = 0;
  for (int t = 0; t < NT; t++) {
    if (t + 1 < NT) stage(cur ^ 1, (t + 1) * BK);  // issue-early prefetch

    const u16* Ab = smem + cur * BUF;
    const u16* Bb = Ab + BM * BK;
    s16x8 af[MF][2], bf[NF][2];
#pragma unroll
    for (int f = 0; f < MF; f++)
#pragma unroll
      for (int kk = 0; kk < 2; kk++)
        af[f][kk] = *(const s16x8*)&Ab[(wm * 64 + f * 16 + fr) * BK + kk * 32 + fg * 8];
#pragma unroll
    for (int j = 0; j < NF; j++)
#pragma unroll
      for (int kk = 0; kk < 2; kk++)
        bf[j][kk] = *(const s16x8*)&Bb[(wn * 64 + j * 16 + fr) * BK + kk * 32 + fg * 8];
#pragma unroll
    for (int kk = 0; kk < 2; kk++)
#pragma unroll
      for (int f = 0; f < MF; f++)
#pragma unroll
        for (int j = 0; j < NF; j++)
          acc[f][j] = __builtin_amdgcn_mfma_f32_16x16x32_bf16(
              af[f][kk], bf[j][kk], acc[f][j], 0, 0, 0);

    __syncthreads();  // drains staged loads; fences reads before overwrite
    cur ^= 1;
  }

  // C-write; C/D layout: col=lane&15, row=(lane>>4)*4+reg  [m89-verified,
  // end-to-end validated by R2/R5 passing absmax]
#pragma unroll
  for (int j = 0; j < NF; j++) {
    const int col = n0 + wn * 64 + j * 16 + fr;
    const float bv = ACT ? bias[col] : 0.f;
#pragma unroll
    for (int f = 0; f < MF; f++) {
#pragma unroll
      for (int q = 0; q < 4; q++) {
        const int row = m0 + wm * 64 + f * 16 + fg * 4 + q;
        if (ACT) {
          float v = acc[f][j][q] + bv;
          v = (v > 0.f) ? v : 0.01f * v;  // jax.nn.leaky_relu default slope
          ((u16*)out)[(size_t)row * N + col] = f2bf(v);
        } else {
          float* o = (float*)out + (size_t)blockIdx.z * M * N;
          o[(size_t)row * N + col] = acc[f][j][q];
        }
      }
    }
  }
}

// ----------------------------------------------------- wave reductions -----

__device__ __forceinline__ float wred_sum(float v) {
#pragma unroll
  for (int o = 32; o; o >>= 1) v += __shfl_xor(v, o, 64);
  return v;
}
__device__ __forceinline__ float wred_max(float v) {
#pragma unroll
  for (int o = 32; o; o >>= 1) v = fmaxf(v, __shfl_xor(v, o, 64));
  return v;
}
__device__ __forceinline__ u32 wred_sumu(u32 v) {
#pragma unroll
  for (int o = 32; o; o >>= 1) v += (u32)__shfl_xor((int)v, o, 64);
  return v;
}

// ------------------------------------------------------------ epilogue -----
// One WAVE per row (4 waves/block, 256 blocks = 1024 rows). Zero barriers,
// zero LDS. INTERLEAVED ownership: register r=g*4+j, lane l <-> column
// c = g*256 + l*4 + j  =>  every float4 load/store instruction covers a
// contiguous 1KB span per wave (full-line, no RFO/partial-write churn).
// logits = p0+p1+p2+p3 + b_dec. Exact k-th largest via bit-serial binary
// search on positive-float bit patterns (monotone as u32):
//   T = max{T : count(y >= T) >= k}  ==  k-th largest value.
// Both thresholds (k=75, k=51) searched simultaneously, counts packed 16+16.
// Monotonicity: top-51-of-pr == top-51-of-y; pr51 = GAIN*exp(c*t51-Mv)/Z
// (holds under ties: tied-at-boundary selected entries share pr value).
// Rare tie-break (need != E): jax keeps lowest global index first; global
// order of (g,j,lane) is (g, lane, j)-lexicographic; rank computed exactly
// from per-register wave ballots (all-lane uniform execution).

__global__ __launch_bounds__(256) void epilogue_wave_kernel(
    const float* __restrict__ p0, const float* __restrict__ p1,
    const float* __restrict__ p2, const float* __restrict__ p3,
    const float* __restrict__ b_dec, const float* __restrict__ targets,
    float* __restrict__ out, float* __restrict__ lossp) {
  const int tid = threadIdx.x;
  const int widx = tid >> 6, lane = tid & 63;
  const int r = blockIdx.x * 4 + widx;
  const size_t rb = (size_t)r * 2048;

  u32 u[32];
  float bce = 0.f, ymax = 0.f;
#pragma unroll
  for (int g = 0; g < 8; g++) {
    const size_t o = rb + g * 256 + lane * 4;
    float4 a = *(const float4*)(p0 + o);
    float4 b = *(const float4*)(p1 + o);
    float4 d = *(const float4*)(p2 + o);
    float4 e = *(const float4*)(p3 + o);
    float4 c4 = *(const float4*)(b_dec + g * 256 + lane * 4);
    float4 t4 = *(const float4*)(targets + o);
    float lv[4] = {a.x + b.x + d.x + e.x + c4.x, a.y + b.y + d.y + e.y + c4.y,
                   a.z + b.z + d.z + e.z + c4.z, a.w + b.w + d.w + e.w + c4.w};
    float tv[4] = {t4.x, t4.y, t4.z, t4.w};
#pragma unroll
    for (int j = 0; j < 4; j++) {
      float li = lv[j];
      bce += fmaxf(li, 0.f) - li * tv[j] + log1pf(expf(-fabsf(li)));
      float yi = 1.f / (1.f + expf(-li));  // in (0,1): clip is a no-op
      u[g * 4 + j] = __float_as_uint(yi);
      ymax = fmaxf(ymax, yi);
    }
  }
  bce = wred_sum(bce);
  if (lane == 0) lossp[r] = bce;
  ymax = wred_max(ymax);

  // dual binary search: y < 1 => bits 31,30 are 0; search bits 29..0
  u32 T75 = 0, T51 = 0;
  for (int b = 29; b >= 0; b--) {
    const u32 c75 = T75 | (1u << b), c51 = T51 | (1u << b);
    u32 cnt = 0;
#pragma unroll
    for (int i = 0; i < 32; i++) {
      cnt += (u[i] >= c75) ? 1u : 0u;
      cnt += (u[i] >= c51) ? 0x10000u : 0u;
    }
    cnt = wred_sumu(cnt);
    if ((cnt & 0xFFFFu) >= 75u) T75 = c75;
    if ((cnt >> 16) >= 51u) T51 = c51;
  }

  // counts & sum over strictly-greater; eq count for tie handling
  u32 cc = 0; float sgt = 0.f;
#pragma unroll
  for (int i = 0; i < 32; i++) {
    if (u[i] > T75)       { cc += 1u; sgt += __uint_as_float(u[i]); }
    else if (u[i] == T75) { cc += 0x10000u; }
  }
  cc = wred_sumu(cc);
  sgt = wred_sum(sgt);
  const u32 G = cc & 0xFFFFu, E = cc >> 16;
  const u32 need = 75u - G;  // 1 <= need <= E
  const float t75f = __uint_as_float(T75);
  const float ysum = sgt + (float)need * t75f;

  // selection mask (bit r = register r selected)
  u32 selmask = 0;
#pragma unroll
  for (int i = 0; i < 32; i++)
    if (u[i] >= T75) selmask |= (1u << i);
  if (need != E) {  // rare: keep lowest-global-index tied entries first
    const u64 ltm = ((u64)1 << lane) - 1ull;  // lanes strictly below
    u32 cum = 0;  // tied count in groups g' < g (whole wave)
#pragma unroll
    for (int g = 0; g < 8; g++) {
      u64 bm[4];
      u32 below = 0, grp = 0;
#pragma unroll
      for (int j = 0; j < 4; j++) {
        bm[j] = __ballot(u[g * 4 + j] == T75);
        below += (u32)__popcll(bm[j] & ltm);
        grp += (u32)__popcll(bm[j]);
      }
      u32 same = 0;  // tied at same (g,lane) with smaller j
#pragma unroll
      for (int j = 0; j < 4; j++) {
        const int r2 = g * 4 + j;
        if (u[r2] == T75) {
          if (cum + below + same >= need) selmask &= ~(1u << r2);
          same++;
        }
      }
      cum += grp;
    }
  }

  // softmax chain: y_masked * (1/sum + eps), softmax (stable), gain
  const float c = 1.f / ysum + 1e-13f;
  const float Mv = c * ymax;  // max of masked-scaled row (top-1 is selected)
  float zs = 0.f;
#pragma unroll
  for (int i = 0; i < 32; i++) {
    float yi = __uint_as_float(u[i]);
    float v = ((selmask >> i) & 1u) ? c * yi : 0.f;
    float e = expf(v - Mv);
    zs += e;
    u[i] = __float_as_uint(e);  // reuse register file
  }
  const float Z = wred_sum(zs);
  const float gZ = 2.f / Z;  // GAIN / Z
  const float shift = 1.f - 2.f * (expf(c * __uint_as_float(T51) - Mv) * gZ);

  float* pr_o = out + 1;
  float* zi_o = out + 1 + 2097152;
  float* zc_o = out + 1 + 4194304;
#pragma unroll
  for (int g = 0; g < 8; g++) {
    float4 pr4, zi4, zc4;
    float e0 = __uint_as_float(u[g * 4 + 0]) * gZ;
    float e1 = __uint_as_float(u[g * 4 + 1]) * gZ;
    float e2 = __uint_as_float(u[g * 4 + 2]) * gZ;
    float e3 = __uint_as_float(u[g * 4 + 3]) * gZ;
    pr4 = make_float4(e0, e1, e2, e3);
    zi4 = make_float4(2.f * e0 - 1.f, 2.f * e1 - 1.f, 2.f * e2 - 1.f,
                      2.f * e3 - 1.f);
    zc4 = make_float4(zi4.x + shift, zi4.y + shift, zi4.z + shift,
                      zi4.w + shift);
    const size_t o = rb + g * 256 + lane * 4;
    *(float4*)(pr_o + o) = pr4;
    *(float4*)(zi_o + o) = zi4;
    *(float4*)(zc_o + o) = zc4;
  }
}

__global__ void loss_reduce_kernel(const float* __restrict__ lp,
                                   float* __restrict__ out) {
  const int tid = threadIdx.x;
  float s = 0.f;
  for (int i = tid; i < 1024; i += 256) s += lp[i];
  __shared__ float sf[4];
  float v = s;
#pragma unroll
  for (int o = 32; o; o >>= 1) v += __shfl_down(v, o, 64);
  if ((tid & 63) == 0) sf[tid >> 6] = v;
  __syncthreads();
  if (tid == 0) out[0] = (sf[0] + sf[1] + sf[2] + sf[3]) * (1.f / (1024.f * 2048.f));
}

// -------------------------------------------------------------- launch -----

extern "C" void kernel_launch(void* const* d_in, const int* in_sizes, int n_in,
                              void* d_out, int out_size, void* d_ws, size_t ws_size,
                              hipStream_t stream) {
  (void)in_sizes; (void)n_in; (void)out_size; (void)ws_size;
  const float* inputs  = (const float*)d_in[0];  // [1024][4096]
  const float* targets = (const float*)d_in[1];  // [1024][2048]
  const float* w_enc   = (const float*)d_in[2];  // [4096][4096]
  const float* b_enc   = (const float*)d_in[3];  // [4096]
  const float* w_dec   = (const float*)d_in[4];  // [4096][2048]
  const float* b_dec   = (const float*)d_in[5];  // [2048]
  float* out = (float*)d_out;

  // 64 MB workspace layout (R2/R5-proven footprint):
  char* ws = (char*)d_ws;
  u16* A16 = (u16*)ws;                      //  8 MB  [0, 8M)   dead post-GEMM1
  u16* W1T = (u16*)(ws + (8u << 20));       // 32 MB  [8M, 40M) dead post-GEMM1
  u16* W2T = (u16*)(ws + (40u << 20));      // 16 MB  [40M,56M)
  u16* H16 = (u16*)(ws + (56u << 20));      //  8 MB  [56M,64M)
  float* lgts  = (float*)(ws + (8u << 20)); // 4x8 MB overlays dead W1T
  float* lossp = (float*)ws;                //  4 KB  overlays dead A16

  // fused prep: cast inputs + transpose-cast both weights (one dispatch)
  prep_kernel<<<28672, 256, 0, stream>>>(inputs, w_enc, w_dec, A16, W1T, W2T);

  // hidden = leaky_relu(A @ W1 + b_enc) -> bf16   (grid 256, 1 block/CU)
  gemm2ph_kernel<1><<<dim3(32, 8), 256, 0, stream>>>(
      A16, W1T, b_enc, (void*)H16, 1024, 4096, 4096, 4096);
  // logits partials = hidden @ W2, K-split 4      (grid 512, 2 blocks/CU)
  gemm2ph_kernel<0><<<dim3(16, 8, 4), 256, 0, stream>>>(
      H16, W2T, nullptr, (void*)lgts, 1024, 2048, 4096, 1024);

  const float* q0 = lgts;
  const float* q1 = lgts + (size_t)2 * 1024 * 1024;
  const float* q2 = lgts + (size_t)4 * 1024 * 1024;
  const float* q3 = lgts + (size_t)6 * 1024 * 1024;
  epilogue_wave_kernel<<<256, 256, 0, stream>>>(q0, q1, q2, q3, b_dec,
                                                targets, out, lossp);
  loss_reduce_kernel<<<1, 256, 0, stream>>>(lossp, out);
}

// Round 7
// 288.470 us; speedup vs baseline: 1.4041x; 1.0020x over previous
//
#include <hip/hip_runtime.h>
#include <hip/hip_bf16.h>

// PerforantPR forward on MI355X (gfx950).
// R7: ONE change vs R6 — epilogue __launch_bounds__(256, 1). R6's counters
// (VGPR_Count=40 for a kernel that must hold u[32] live across a 30-iter
// loop) prove the array was spilled to scratch; the binary search re-read
// all 32 spilled values x30 iters => latency-bound at 430 GB/s. Grid is
// 1024 waves (1/SIMD) so high-occupancy VGPR budgets buy nothing here.
//
// B=1024, D_IN=4096, D_HID=4096, D_OUT=2048, K_PR=75, K_SHIFT=51.

typedef unsigned short u16;
typedef unsigned int u32;
typedef unsigned long long u64;
typedef __attribute__((ext_vector_type(4))) float f32x4;
typedef __attribute__((ext_vector_type(8))) short s16x8;

#define GAS __attribute__((address_space(1)))
#define LAS __attribute__((address_space(3)))

__device__ __forceinline__ u16 f2bf(float x) {
  u32 u = __float_as_uint(x);
  u32 r = (u + 0x7FFFu + ((u >> 16) & 1u)) >> 16;  // RNE; no NaN inputs here
  return (u16)r;
}

__device__ __forceinline__ void gld_lds16(const u16* g, u16* l) {
  // async global->LDS, 16B per lane; LDS dest = wave-uniform base + lane*16
  __builtin_amdgcn_global_load_lds((const GAS void*)g, (LAS void*)l, 16, 0, 0);
}

// ------------------------------------------------------------ fused prep ---
// blocks [0,4096): cast inputs f32->bf16 (uint2 stores)
// blocks [4096,20480): transpose-cast w_enc [4096][4096] -> W1T
// blocks [20480,28672): transpose-cast w_dec [4096][2048] -> W2T

__device__ __forceinline__ void tcast_body(const float* __restrict__ in,
                                           u16* __restrict__ out, int R, int C,
                                           int bx, int by, int tid) {
  __shared__ float tile[32][33];
  const int cb = bx * 32, rb = by * 32;
  const int tx = tid & 31, ty = tid >> 5;  // 32 x 8
#pragma unroll
  for (int i = 0; i < 4; i++)
    tile[ty + i * 8][tx] = in[(size_t)(rb + ty + i * 8) * C + cb + tx];
  __syncthreads();
#pragma unroll
  for (int i = 0; i < 4; i++)
    out[(size_t)(cb + ty + i * 8) * R + rb + tx] = f2bf(tile[tx][ty + i * 8]);
}

__global__ __launch_bounds__(256) void prep_kernel(
    const float* __restrict__ inputs, const float* __restrict__ w_enc,
    const float* __restrict__ w_dec, u16* __restrict__ A16,
    u16* __restrict__ W1T, u16* __restrict__ W2T) {
  const int bid = blockIdx.x, tid = threadIdx.x;
  if (bid < 4096) {
    const int i = bid * 256 + tid;  // n4 = 1024*4096/4 = exactly 4096*256
    float4 v = ((const float4*)inputs)[i];
    uint2 p;
    p.x = (u32)f2bf(v.x) | ((u32)f2bf(v.y) << 16);
    p.y = (u32)f2bf(v.z) | ((u32)f2bf(v.w) << 16);
    ((uint2*)A16)[i] = p;
  } else if (bid < 20480) {
    const int idx = bid - 4096;  // 128 x 128 tiles
    tcast_body(w_enc, W1T, 4096, 4096, idx & 127, idx >> 7, tid);
  } else {
    const int idx = bid - 20480;  // 64 x 128 tiles
    tcast_body(w_dec, W2T, 4096, 2048, idx & 63, idx >> 6, tid);
  }
}

// ----------------------------------------------------------------- GEMM ----
// 2-phase pipelined: C[m][n] = sum_k A[m][k]*BT[n][k], A:[M][K], BT:[N][K].
// 128x128 tile, BK=64, 4 waves (2x2) of 64x64, double-buffered LDS (64 KB).
// Per K-step: STAGE next tile (8 gld_lds16/wave) -> ds_read+32 MFMA on
// current -> one __syncthreads() (drains vmcnt for the staged buffer AND
// fences reads of the current buffer before it is overwritten next iter).
// ACT=1: +bias, leaky_relu(0.01), bf16 out (z==0 only).
// ACT=0: raw f32 partial over k in [z*klen,(z+1)*klen) -> out + z*M*N.
// Consistent-slot trick: A and B fragments use the same (lane,reg)->k map
// (row=lane&15, 8-elem chunk = (kk,lane>>4)) => MFMA pairs identical k-slots.

template <int ACT>
__global__ __launch_bounds__(256, 2) void gemm2ph_kernel(
    const u16* __restrict__ A, const u16* __restrict__ BT,
    const float* __restrict__ bias, void* __restrict__ out,
    int M, int N, int K, int klen) {
  constexpr int BM = 128, BN = 128, BK = 64;
  constexpr int MF = 4, NF = 4;  // 64x64 per wave
  constexpr int BUF = BM * BK + BN * BK;  // elements per buffer
  __shared__ __align__(16) u16 smem[2 * BUF];  // 64 KB

  const int tid = threadIdx.x;
  const int wid = tid >> 6, lane = tid & 63;
  const int wm = wid >> 1, wn = wid & 1;
  const int n0 = blockIdx.x * BN, m0 = blockIdx.y * BM;
  const int kbase = blockIdx.z * klen;

  f32x4 acc[MF][NF];
#pragma unroll
  for (int f = 0; f < MF; f++)
#pragma unroll
    for (int j = 0; j < NF; j++) acc[f][j] = (f32x4)0.f;

  // staging inst i covers 8 rows [i*8, i*8+8): lane l -> row i*8 + (l>>3),
  // 16B chunk (l&7); LDS linear dest (l>>3)*128B + (l&7)*16B == l*16B.
  const u16* Ag = A + (size_t)(m0 + (lane >> 3)) * K + kbase + (lane & 7) * 8;
  const u16* Bg = BT + (size_t)(n0 + (lane >> 3)) * K + kbase + (lane & 7) * 8;
  const int fr = lane & 15, fg = lane >> 4;
  const int NT = klen / BK;

  auto stage = [&](int b, int koff) {
    u16* Al = smem + b * BUF;
    u16* Bl = Al + BM * BK;
#pragma unroll
    for (int t2 = 0; t2 < 4; t2++) {
      const int i = wid * 4 + t2;  // 16 insts for A, 16 for B, 4+4 per wave
      gld_lds16(Ag + (size_t)i * 8 * K + koff, Al + i * 512);
      gld_lds16(Bg + (size_t)i * 8 * K + koff, Bl + i * 512);
    }
  };

  stage(0, 0);
  __syncthreads();
  int cur = 0;
  for (int t = 0; t < NT; t++) {
    if (t + 1 < NT) stage(cur ^ 1, (t + 1) * BK);  // issue-early prefetch

    const u16* Ab = smem + cur * BUF;
    const u16* Bb = Ab + BM * BK;
    s16x8 af[MF][2], bf[NF][2];
#pragma unroll
    for (int f = 0; f < MF; f++)
#pragma unroll
      for (int kk = 0; kk < 2; kk++)
        af[f][kk] = *(const s16x8*)&Ab[(wm * 64 + f * 16 + fr) * BK + kk * 32 + fg * 8];
#pragma unroll
    for (int j = 0; j < NF; j++)
#pragma unroll
      for (int kk = 0; kk < 2; kk++)
        bf[j][kk] = *(const s16x8*)&Bb[(wn * 64 + j * 16 + fr) * BK + kk * 32 + fg * 8];
#pragma unroll
    for (int kk = 0; kk < 2; kk++)
#pragma unroll
      for (int f = 0; f < MF; f++)
#pragma unroll
        for (int j = 0; j < NF; j++)
          acc[f][j] = __builtin_amdgcn_mfma_f32_16x16x32_bf16(
              af[f][kk], bf[j][kk], acc[f][j], 0, 0, 0);

    __syncthreads();  // drains staged loads; fences reads before overwrite
    cur ^= 1;
  }

  // C-write; C/D layout: col=lane&15, row=(lane>>4)*4+reg  [m89-verified,
  // end-to-end validated by R2/R5/R6 passing absmax]
#pragma unroll
  for (int j = 0; j < NF; j++) {
    const int col = n0 + wn * 64 + j * 16 + fr;
    const float bv = ACT ? bias[col] : 0.f;
#pragma unroll
    for (int f = 0; f < MF; f++) {
#pragma unroll
      for (int q = 0; q < 4; q++) {
        const int row = m0 + wm * 64 + f * 16 + fg * 4 + q;
        if (ACT) {
          float v = acc[f][j][q] + bv;
          v = (v > 0.f) ? v : 0.01f * v;  // jax.nn.leaky_relu default slope
          ((u16*)out)[(size_t)row * N + col] = f2bf(v);
        } else {
          float* o = (float*)out + (size_t)blockIdx.z * M * N;
          o[(size_t)row * N + col] = acc[f][j][q];
        }
      }
    }
  }
}

// ----------------------------------------------------- wave reductions -----

__device__ __forceinline__ float wred_sum(float v) {
#pragma unroll
  for (int o = 32; o; o >>= 1) v += __shfl_xor(v, o, 64);
  return v;
}
__device__ __forceinline__ float wred_max(float v) {
#pragma unroll
  for (int o = 32; o; o >>= 1) v = fmaxf(v, __shfl_xor(v, o, 64));
  return v;
}
__device__ __forceinline__ u32 wred_sumu(u32 v) {
#pragma unroll
  for (int o = 32; o; o >>= 1) v += (u32)__shfl_xor((int)v, o, 64);
  return v;
}

// ------------------------------------------------------------ epilogue -----
// One WAVE per row (4 waves/block, 256 blocks = 1024 rows). Zero barriers,
// zero LDS. INTERLEAVED ownership: register r=g*4+j, lane l <-> column
// c = g*256 + l*4 + j  =>  every float4 load/store instruction covers a
// contiguous 1KB span per wave (full-line, no RFO/partial-write churn).
// __launch_bounds__(256, 1): grid is 1024 waves = 1 wave/SIMD, so cap the
// occupancy target at 1 wave/EU -> VGPR budget up to 512 -> u[32] + the
// 6-stream load pipeline stay IN REGISTERS (R6's VGPR_Count=40 proved the
// array spilled to scratch; 30-iter search re-read it 960x per thread).
// logits = p0+p1+p2+p3 + b_dec. Exact k-th largest via bit-serial binary
// search on positive-float bit patterns (monotone as u32):
//   T = max{T : count(y >= T) >= k}  ==  k-th largest value.
// Both thresholds (k=75, k=51) searched simultaneously, counts packed 16+16.
// Monotonicity: top-51-of-pr == top-51-of-y; pr51 = GAIN*exp(c*t51-Mv)/Z
// (holds under ties: tied-at-boundary selected entries share pr value).
// Rare tie-break (need != E): jax keeps lowest global index first; global
// order of (g,j,lane) is (g, lane, j)-lexicographic; rank computed exactly
// from per-register wave ballots (all-lane uniform execution).

__global__ __launch_bounds__(256, 1) void epilogue_wave_kernel(
    const float* __restrict__ p0, const float* __restrict__ p1,
    const float* __restrict__ p2, const float* __restrict__ p3,
    const float* __restrict__ b_dec, const float* __restrict__ targets,
    float* __restrict__ out, float* __restrict__ lossp) {
  const int tid = threadIdx.x;
  const int widx = tid >> 6, lane = tid & 63;
  const int r = blockIdx.x * 4 + widx;
  const size_t rb = (size_t)r * 2048;

  u32 u[32];
  float bce = 0.f, ymax = 0.f;
#pragma unroll
  for (int g = 0; g < 8; g++) {
    const size_t o = rb + g * 256 + lane * 4;
    float4 a = *(const float4*)(p0 + o);
    float4 b = *(const float4*)(p1 + o);
    float4 d = *(const float4*)(p2 + o);
    float4 e = *(const float4*)(p3 + o);
    float4 c4 = *(const float4*)(b_dec + g * 256 + lane * 4);
    float4 t4 = *(const float4*)(targets + o);
    float lv[4] = {a.x + b.x + d.x + e.x + c4.x, a.y + b.y + d.y + e.y + c4.y,
                   a.z + b.z + d.z + e.z + c4.z, a.w + b.w + d.w + e.w + c4.w};
    float tv[4] = {t4.x, t4.y, t4.z, t4.w};
#pragma unroll
    for (int j = 0; j < 4; j++) {
      float li = lv[j];
      bce += fmaxf(li, 0.f) - li * tv[j] + log1pf(expf(-fabsf(li)));
      float yi = 1.f / (1.f + expf(-li));  // in (0,1): clip is a no-op
      u[g * 4 + j] = __float_as_uint(yi);
      ymax = fmaxf(ymax, yi);
    }
  }
  bce = wred_sum(bce);
  if (lane == 0) lossp[r] = bce;
  ymax = wred_max(ymax);

  // dual binary search: y < 1 => bits 31,30 are 0; search bits 29..0
  u32 T75 = 0, T51 = 0;
  for (int b = 29; b >= 0; b--) {
    const u32 c75 = T75 | (1u << b), c51 = T51 | (1u << b);
    u32 cnt = 0;
#pragma unroll
    for (int i = 0; i < 32; i++) {
      cnt += (u[i] >= c75) ? 1u : 0u;
      cnt += (u[i] >= c51) ? 0x10000u : 0u;
    }
    cnt = wred_sumu(cnt);
    if ((cnt & 0xFFFFu) >= 75u) T75 = c75;
    if ((cnt >> 16) >= 51u) T51 = c51;
  }

  // counts & sum over strictly-greater; eq count for tie handling
  u32 cc = 0; float sgt = 0.f;
#pragma unroll
  for (int i = 0; i < 32; i++) {
    if (u[i] > T75)       { cc += 1u; sgt += __uint_as_float(u[i]); }
    else if (u[i] == T75) { cc += 0x10000u; }
  }
  cc = wred_sumu(cc);
  sgt = wred_sum(sgt);
  const u32 G = cc & 0xFFFFu, E = cc >> 16;
  const u32 need = 75u - G;  // 1 <= need <= E
  const float t75f = __uint_as_float(T75);
  const float ysum = sgt + (float)need * t75f;

  // selection mask (bit r = register r selected)
  u32 selmask = 0;
#pragma unroll
  for (int i = 0; i < 32; i++)
    if (u[i] >= T75) selmask |= (1u << i);
  if (need != E) {  // rare: keep lowest-global-index tied entries first
    const u64 ltm = ((u64)1 << lane) - 1ull;  // lanes strictly below
    u32 cum = 0;  // tied count in groups g' < g (whole wave)
#pragma unroll
    for (int g = 0; g < 8; g++) {
      u64 bm[4];
      u32 below = 0, grp = 0;
#pragma unroll
      for (int j = 0; j < 4; j++) {
        bm[j] = __ballot(u[g * 4 + j] == T75);
        below += (u32)__popcll(bm[j] & ltm);
        grp += (u32)__popcll(bm[j]);
      }
      u32 same = 0;  // tied at same (g,lane) with smaller j
#pragma unroll
      for (int j = 0; j < 4; j++) {
        const int r2 = g * 4 + j;
        if (u[r2] == T75) {
          if (cum + below + same >= need) selmask &= ~(1u << r2);
          same++;
        }
      }
      cum += grp;
    }
  }

  // softmax chain: y_masked * (1/sum + eps), softmax (stable), gain
  const float c = 1.f / ysum + 1e-13f;
  const float Mv = c * ymax;  // max of masked-scaled row (top-1 is selected)
  float zs = 0.f;
#pragma unroll
  for (int i = 0; i < 32; i++) {
    float yi = __uint_as_float(u[i]);
    float v = ((selmask >> i) & 1u) ? c * yi : 0.f;
    float e = expf(v - Mv);
    zs += e;
    u[i] = __float_as_uint(e);  // reuse register file
  }
  const float Z = wred_sum(zs);
  const float gZ = 2.f / Z;  // GAIN / Z
  const float shift = 1.f - 2.f * (expf(c * __uint_as_float(T51) - Mv) * gZ);

  float* pr_o = out + 1;
  float* zi_o = out + 1 + 2097152;
  float* zc_o = out + 1 + 4194304;
#pragma unroll
  for (int g = 0; g < 8; g++) {
    float4 pr4, zi4, zc4;
    float e0 = __uint_as_float(u[g * 4 + 0]) * gZ;
    float e1 = __uint_as_float(u[g * 4 + 1]) * gZ;
    float e2 = __uint_as_float(u[g * 4 + 2]) * gZ;
    float e3 = __uint_as_float(u[g * 4 + 3]) * gZ;
    pr4 = make_float4(e0, e1, e2, e3);
    zi4 = make_float4(2.f * e0 - 1.f, 2.f * e1 - 1.f, 2.f * e2 - 1.f,
                      2.f * e3 - 1.f);
    zc4 = make_float4(zi4.x + shift, zi4.y + shift, zi4.z + shift,
                      zi4.w + shift);
    const size_t o = rb + g * 256 + lane * 4;
    *(float4*)(pr_o + o) = pr4;
    *(float4*)(zi_o + o) = zi4;
    *(float4*)(zc_o + o) = zc4;
  }
}

__global__ void loss_reduce_kernel(const float* __restrict__ lp,
                                   float* __restrict__ out) {
  const int tid = threadIdx.x;
  float s = 0.f;
  for (int i = tid; i < 1024; i += 256) s += lp[i];
  __shared__ float sf[4];
  float v = s;
#pragma unroll
  for (int o = 32; o; o >>= 1) v += __shfl_down(v, o, 64);
  if ((tid & 63) == 0) sf[tid >> 6] = v;
  __syncthreads();
  if (tid == 0) out[0] = (sf[0] + sf[1] + sf[2] + sf[3]) * (1.f / (1024.f * 2048.f));
}

// -------------------------------------------------------------- launch -----

extern "C" void kernel_launch(void* const* d_in, const int* in_sizes, int n_in,
                              void* d_out, int out_size, void* d_ws, size_t ws_size,
                              hipStream_t stream) {
  (void)in_sizes; (void)n_in; (void)out_size; (void)ws_size;
  const float* inputs  = (const float*)d_in[0];  // [1024][4096]
  const float* targets = (const float*)d_in[1];  // [1024][2048]
  const float* w_enc   = (const float*)d_in[2];  // [4096][4096]
  const float* b_enc   = (const float*)d_in[3];  // [4096]
  const float* w_dec   = (const float*)d_in[4];  // [4096][2048]
  const float* b_dec   = (const float*)d_in[5];  // [2048]
  float* out = (float*)d_out;

  // 64 MB workspace layout (R2/R5/R6-proven footprint):
  char* ws = (char*)d_ws;
  u16* A16 = (u16*)ws;                      //  8 MB  [0, 8M)   dead post-GEMM1
  u16* W1T = (u16*)(ws + (8u << 20));       // 32 MB  [8M, 40M) dead post-GEMM1
  u16* W2T = (u16*)(ws + (40u << 20));      // 16 MB  [40M,56M)
  u16* H16 = (u16*)(ws + (56u << 20));      //  8 MB  [56M,64M)
  float* lgts  = (float*)(ws + (8u << 20)); // 4x8 MB overlays dead W1T
  float* lossp = (float*)ws;                //  4 KB  overlays dead A16

  // fused prep: cast inputs + transpose-cast both weights (one dispatch)
  prep_kernel<<<28672, 256, 0, stream>>>(inputs, w_enc, w_dec, A16, W1T, W2T);

  // hidden = leaky_relu(A @ W1 + b_enc) -> bf16   (grid 256, 1 block/CU)
  gemm2ph_kernel<1><<<dim3(32, 8), 256, 0, stream>>>(
      A16, W1T, b_enc, (void*)H16, 1024, 4096, 4096, 4096);
  // logits partials = hidden @ W2, K-split 4      (grid 512, 2 blocks/CU)
  gemm2ph_kernel<0><<<dim3(16, 8, 4), 256, 0, stream>>>(
      H16, W2T, nullptr, (void*)lgts, 1024, 2048, 4096, 1024);

  const float* q0 = lgts;
  const float* q1 = lgts + (size_t)2 * 1024 * 1024;
  const float* q2 = lgts + (size_t)4 * 1024 * 1024;
  const float* q3 = lgts + (size_t)6 * 1024 * 1024;
  epilogue_wave_kernel<<<256, 256, 0, stream>>>(q0, q1, q2, q3, b_dec,
                                                targets, out, lossp);
  loss_reduce_kernel<<<1, 256, 0, stream>>>(lossp, out);
}

// Round 8
// 281.465 us; speedup vs baseline: 1.4390x; 1.0249x over previous
//
#include <hip/hip_runtime.h>
#include <hip/hip_bf16.h>

// PerforantPR forward on MI355X (gfx950).
// R8 vs R7 (GEMM1 was top: 62us, 551 TF, MfmaUtil 20%, 1.26e7 bank conflicts,
// 1 wave/SIMD):
//  1) GEMM: static x2-unrolled double buffer (compile-time LDS pointers) so
//     LLVM can disambiguate gld_lds writes vs ds_reads -> prefetch overlaps.
//  2) GEMM: XOR granule swizzle (pre-swizzled gld_lds SOURCE + swizzled
//     ds_read addr; LDS dest stays linear) -> b128 reads at the 8-cy floor.
//  3) prep transpose: 64x32 tiles, 128B full-line writes (kills write RFO).
//
// B=1024, D_IN=4096, D_HID=4096, D_OUT=2048, K_PR=75, K_SHIFT=51.

typedef unsigned short u16;
typedef unsigned int u32;
typedef unsigned long long u64;
typedef __attribute__((ext_vector_type(4))) float f32x4;
typedef __attribute__((ext_vector_type(8))) short s16x8;

#define GAS __attribute__((address_space(1)))
#define LAS __attribute__((address_space(3)))

__device__ __forceinline__ u16 f2bf(float x) {
  u32 u = __float_as_uint(x);
  u32 r = (u + 0x7FFFu + ((u >> 16) & 1u)) >> 16;  // RNE; no NaN inputs here
  return (u16)r;
}

__device__ __forceinline__ void gld_lds16(const u16* g, u16* l) {
  // async global->LDS, 16B per lane; LDS dest = wave-uniform base + lane*16
  __builtin_amdgcn_global_load_lds((const GAS void*)g, (LAS void*)l, 16, 0, 0);
}

// ------------------------------------------------------------ fused prep ---
// blocks [0,4096):      cast inputs f32->bf16 (uint2 stores)
// blocks [4096,12288):  transpose-cast w_enc [4096][4096] -> W1T
// blocks [12288,16384): transpose-cast w_dec [4096][2048] -> W2T
// Transpose tile: 64 src-rows x 32 src-cols; out-row = src-col, written as
// 32 lanes x u32 = 128B full cache line (R7 wrote 64B halves -> RFO churn).

__device__ __forceinline__ void tcast_body(const float* __restrict__ in,
                                           u16* __restrict__ out, int R, int C,
                                           int bx, int by, int tid) {
  __shared__ float tile[64][33];
  const int cb = bx * 32, rb = by * 64;
  const int tx = tid & 31, ty = tid >> 5;  // (32,8)
#pragma unroll
  for (int i = 0; i < 8; i++)
    tile[ty + i * 8][tx] = in[(size_t)(rb + ty + i * 8) * C + cb + tx];
  __syncthreads();
#pragma unroll
  for (int i = 0; i < 4; i++) {
    const int oc = ty + i * 8;  // out row = src col cb+oc
    float v0 = tile[2 * tx][oc], v1 = tile[2 * tx + 1][oc];
    u32 p = (u32)f2bf(v0) | ((u32)f2bf(v1) << 16);
    *(u32*)(out + (size_t)(cb + oc) * R + rb + 2 * tx) = p;
  }
}

__global__ __launch_bounds__(256) void prep_kernel(
    const float* __restrict__ inputs, const float* __restrict__ w_enc,
    const float* __restrict__ w_dec, u16* __restrict__ A16,
    u16* __restrict__ W1T, u16* __restrict__ W2T) {
  const int bid = blockIdx.x, tid = threadIdx.x;
  if (bid < 4096) {
    const int i = bid * 256 + tid;  // n4 = 1024*4096/4 = exactly 4096*256
    float4 v = ((const float4*)inputs)[i];
    uint2 p;
    p.x = (u32)f2bf(v.x) | ((u32)f2bf(v.y) << 16);
    p.y = (u32)f2bf(v.z) | ((u32)f2bf(v.w) << 16);
    ((uint2*)A16)[i] = p;
  } else if (bid < 12288) {
    const int idx = bid - 4096;  // 128 bx x 64 by
    tcast_body(w_enc, W1T, 4096, 4096, idx & 127, idx >> 7, tid);
  } else {
    const int idx = bid - 12288;  // 64 bx x 64 by
    tcast_body(w_dec, W2T, 4096, 2048, idx & 63, idx >> 6, tid);
  }
}

// ----------------------------------------------------------------- GEMM ----
// 2-phase pipelined: C[m][n] = sum_k A[m][k]*BT[n][k], A:[M][K], BT:[N][K].
// 128x128 tile, BK=64, 4 waves (2x2) of 64x64, double-buffered LDS (64 KB)
// with STATIC buffer pointers (x2-unrolled K loop) so the compiler can prove
// stage-writes don't alias compute-reads, and the staged loads stay in
// flight under ds_read+MFMA until the barrier's vmcnt(0).
// LDS granule swizzle (16B granules, 8/row): LDS(row, g) holds global
// granule g^(row&7). Staging: lane l sources granule (l&7)^((l>>3)&7), LDS
// dest stays linear (gld_lds requirement). ds_read: granule (kk*4+fg)^(fr&7)
// -> per-instruction lanes spread over all 8 bank-quads (8-cy floor; the
// unswizzled version concentrated 16 lanes on 4 banks = 16-way conflict).
// ACT=1: +bias, leaky_relu(0.01), bf16 out (z==0 only).
// ACT=0: raw f32 partial over k in [z*klen,(z+1)*klen) -> out + z*M*N.
// Consistent-slot trick: A and B fragments use the same (lane,reg)->k map
// => MFMA pairs identical k-slots => dot product exact.

template <int ACT>
__global__ __launch_bounds__(256, 2) void gemm2ph_kernel(
    const u16* __restrict__ A, const u16* __restrict__ BT,
    const float* __restrict__ bias, void* __restrict__ out,
    int M, int N, int K, int klen) {
  constexpr int BM = 128, BN = 128, BK = 64;
  constexpr int MF = 4, NF = 4;            // 64x64 per wave
  constexpr int BUF = BM * BK + BN * BK;   // elements per buffer
  __shared__ __align__(16) u16 smem[2 * BUF];  // 64 KB

  const int tid = threadIdx.x;
  const int wid = tid >> 6, lane = tid & 63;
  const int wm = wid >> 1, wn = wid & 1;
  const int n0 = blockIdx.x * BN, m0 = blockIdx.y * BM;
  const int kbase = blockIdx.z * klen;

  u16* const A0 = smem;
  u16* const B0 = smem + BM * BK;
  u16* const A1 = smem + BUF;
  u16* const B1 = smem + BUF + BM * BK;

  f32x4 acc[MF][NF];
#pragma unroll
  for (int f = 0; f < MF; f++)
#pragma unroll
    for (int j = 0; j < NF; j++) acc[f][j] = (f32x4)0.f;

  // staging inst i covers 8 rows [i*8,i*8+8): lane l -> row i*8+(l>>3);
  // SOURCE granule (l&7)^((l>>3)&7) (inverse swizzle); LDS dest linear l*16.
  const int sg = (lane & 7) ^ ((lane >> 3) & 7);
  const u16* Ag = A + (size_t)(m0 + (lane >> 3)) * K + kbase + sg * 8;
  const u16* Bg = BT + (size_t)(n0 + (lane >> 3)) * K + kbase + sg * 8;
  const int fr = lane & 15, fg = lane >> 4;
  const int NT = klen / BK;  // 64 (GEMM1) / 16 (GEMM2), always even

  auto stage = [&](u16* __restrict__ Al, u16* __restrict__ Bl, int koff) {
#pragma unroll
    for (int t2 = 0; t2 < 4; t2++) {
      const int i = wid * 4 + t2;  // 16 insts for A, 16 for B; 4+4 per wave
      gld_lds16(Ag + (size_t)i * 8 * K + koff, Al + i * 512);
      gld_lds16(Bg + (size_t)i * 8 * K + koff, Bl + i * 512);
    }
  };

  const int swz = fr & 7;
  auto compute = [&](const u16* __restrict__ Ab, const u16* __restrict__ Bb) {
    s16x8 af[MF][2], bf[NF][2];
#pragma unroll
    for (int f = 0; f < MF; f++)
#pragma unroll
      for (int kk = 0; kk < 2; kk++)
        af[f][kk] = *(const s16x8*)
            &Ab[(wm * 64 + f * 16 + fr) * BK + (((kk * 4 + fg) ^ swz) * 8)];
#pragma unroll
    for (int j = 0; j < NF; j++)
#pragma unroll
      for (int kk = 0; kk < 2; kk++)
        bf[j][kk] = *(const s16x8*)
            &Bb[(wn * 64 + j * 16 + fr) * BK + (((kk * 4 + fg) ^ swz) * 8)];
#pragma unroll
    for (int kk = 0; kk < 2; kk++)
#pragma unroll
      for (int f = 0; f < MF; f++)
#pragma unroll
        for (int j = 0; j < NF; j++)
          acc[f][j] = __builtin_amdgcn_mfma_f32_16x16x32_bf16(
              af[f][kk], bf[j][kk], acc[f][j], 0, 0, 0);
  };

  stage(A0, B0, 0);
  __syncthreads();  // vmcnt(0)+barrier: tile 0 resident for all waves
  for (int t = 0; t < NT; t += 2) {
    if (t + 1 < NT) stage(A1, B1, (t + 1) * BK);  // overlaps compute(A0)
    compute(A0, B0);
    __syncthreads();  // all reads of buf0 retired; buf1 loads resident
    if (t + 2 < NT) stage(A0, B0, (t + 2) * BK);  // overlaps compute(A1)
    compute(A1, B1);
    __syncthreads();
  }

  // C-write; C/D layout: col=lane&15, row=(lane>>4)*4+reg  [m89-verified,
  // end-to-end validated by R2..R7 passing absmax]
#pragma unroll
  for (int j = 0; j < NF; j++) {
    const int col = n0 + wn * 64 + j * 16 + fr;
    const float bv = ACT ? bias[col] : 0.f;
#pragma unroll
    for (int f = 0; f < MF; f++) {
#pragma unroll
      for (int q = 0; q < 4; q++) {
        const int row = m0 + wm * 64 + f * 16 + fg * 4 + q;
        if (ACT) {
          float v = acc[f][j][q] + bv;
          v = (v > 0.f) ? v : 0.01f * v;  // jax.nn.leaky_relu default slope
          ((u16*)out)[(size_t)row * N + col] = f2bf(v);
        } else {
          float* o = (float*)out + (size_t)blockIdx.z * M * N;
          o[(size_t)row * N + col] = acc[f][j][q];
        }
      }
    }
  }
}

// ----------------------------------------------------- wave reductions -----

__device__ __forceinline__ float wred_sum(float v) {
#pragma unroll
  for (int o = 32; o; o >>= 1) v += __shfl_xor(v, o, 64);
  return v;
}
__device__ __forceinline__ float wred_max(float v) {
#pragma unroll
  for (int o = 32; o; o >>= 1) v = fmaxf(v, __shfl_xor(v, o, 64));
  return v;
}
__device__ __forceinline__ u32 wred_sumu(u32 v) {
#pragma unroll
  for (int o = 32; o; o >>= 1) v += (u32)__shfl_xor((int)v, o, 64);
  return v;
}

// ------------------------------------------------------------ epilogue -----
// One WAVE per row (4 waves/block, 256 blocks = 1024 rows). Zero barriers,
// zero LDS. INTERLEAVED ownership: register r=g*4+j, lane l <-> column
// c = g*256 + l*4 + j  =>  every float4 load/store instruction covers a
// contiguous 1KB span per wave. __launch_bounds__(256,1): grid is 1 wave/SIMD
// so the VGPR budget is the full file -> u[32] stays in registers.
// logits = p0+p1+p2+p3 + b_dec. Exact k-th largest via bit-serial binary
// search on positive-float bit patterns (monotone as u32). Both thresholds
// (k=75, k=51) searched simultaneously, counts packed 16+16.
// Monotonicity: top-51-of-pr == top-51-of-y; pr51 = GAIN*exp(c*t51-Mv)/Z.
// Rare tie-break (need != E): ballot-rank in (g, lane, j) global order.

__global__ __launch_bounds__(256, 1) void epilogue_wave_kernel(
    const float* __restrict__ p0, const float* __restrict__ p1,
    const float* __restrict__ p2, const float* __restrict__ p3,
    const float* __restrict__ b_dec, const float* __restrict__ targets,
    float* __restrict__ out, float* __restrict__ lossp) {
  const int tid = threadIdx.x;
  const int widx = tid >> 6, lane = tid & 63;
  const int r = blockIdx.x * 4 + widx;
  const size_t rb = (size_t)r * 2048;

  u32 u[32];
  float bce = 0.f, ymax = 0.f;
#pragma unroll
  for (int g = 0; g < 8; g++) {
    const size_t o = rb + g * 256 + lane * 4;
    float4 a = *(const float4*)(p0 + o);
    float4 b = *(const float4*)(p1 + o);
    float4 d = *(const float4*)(p2 + o);
    float4 e = *(const float4*)(p3 + o);
    float4 c4 = *(const float4*)(b_dec + g * 256 + lane * 4);
    float4 t4 = *(const float4*)(targets + o);
    float lv[4] = {a.x + b.x + d.x + e.x + c4.x, a.y + b.y + d.y + e.y + c4.y,
                   a.z + b.z + d.z + e.z + c4.z, a.w + b.w + d.w + e.w + c4.w};
    float tv[4] = {t4.x, t4.y, t4.z, t4.w};
#pragma unroll
    for (int j = 0; j < 4; j++) {
      float li = lv[j];
      bce += fmaxf(li, 0.f) - li * tv[j] + log1pf(expf(-fabsf(li)));
      float yi = 1.f / (1.f + expf(-li));  // in (0,1): clip is a no-op
      u[g * 4 + j] = __float_as_uint(yi);
      ymax = fmaxf(ymax, yi);
    }
  }
  bce = wred_sum(bce);
  if (lane == 0) lossp[r] = bce;
  ymax = wred_max(ymax);

  // dual binary search: y < 1 => bits 31,30 are 0; search bits 29..0
  u32 T75 = 0, T51 = 0;
  for (int b = 29; b >= 0; b--) {
    const u32 c75 = T75 | (1u << b), c51 = T51 | (1u << b);
    u32 cnt = 0;
#pragma unroll
    for (int i = 0; i < 32; i++) {
      cnt += (u[i] >= c75) ? 1u : 0u;
      cnt += (u[i] >= c51) ? 0x10000u : 0u;
    }
    cnt = wred_sumu(cnt);
    if ((cnt & 0xFFFFu) >= 75u) T75 = c75;
    if ((cnt >> 16) >= 51u) T51 = c51;
  }

  // counts & sum over strictly-greater; eq count for tie handling
  u32 cc = 0; float sgt = 0.f;
#pragma unroll
  for (int i = 0; i < 32; i++) {
    if (u[i] > T75)       { cc += 1u; sgt += __uint_as_float(u[i]); }
    else if (u[i] == T75) { cc += 0x10000u; }
  }
  cc = wred_sumu(cc);
  sgt = wred_sum(sgt);
  const u32 G = cc & 0xFFFFu, E = cc >> 16;
  const u32 need = 75u - G;  // 1 <= need <= E
  const float t75f = __uint_as_float(T75);
  const float ysum = sgt + (float)need * t75f;

  // selection mask (bit r = register r selected)
  u32 selmask = 0;
#pragma unroll
  for (int i = 0; i < 32; i++)
    if (u[i] >= T75) selmask |= (1u << i);
  if (need != E) {  // rare: keep lowest-global-index tied entries first
    const u64 ltm = ((u64)1 << lane) - 1ull;  // lanes strictly below
    u32 cum = 0;  // tied count in groups g' < g (whole wave)
#pragma unroll
    for (int g = 0; g < 8; g++) {
      u64 bm[4];
      u32 below = 0, grp = 0;
#pragma unroll
      for (int j = 0; j < 4; j++) {
        bm[j] = __ballot(u[g * 4 + j] == T75);
        below += (u32)__popcll(bm[j] & ltm);
        grp += (u32)__popcll(bm[j]);
      }
      u32 same = 0;  // tied at same (g,lane) with smaller j
#pragma unroll
      for (int j = 0; j < 4; j++) {
        const int r2 = g * 4 + j;
        if (u[r2] == T75) {
          if (cum + below + same >= need) selmask &= ~(1u << r2);
          same++;
        }
      }
      cum += grp;
    }
  }

  // softmax chain: y_masked * (1/sum + eps), softmax (stable), gain
  const float c = 1.f / ysum + 1e-13f;
  const float Mv = c * ymax;  // max of masked-scaled row (top-1 is selected)
  float zs = 0.f;
#pragma unroll
  for (int i = 0; i < 32; i++) {
    float yi = __uint_as_float(u[i]);
    float v = ((selmask >> i) & 1u) ? c * yi : 0.f;
    float e = expf(v - Mv);
    zs += e;
    u[i] = __float_as_uint(e);  // reuse register file
  }
  const float Z = wred_sum(zs);
  const float gZ = 2.f / Z;  // GAIN / Z
  const float shift = 1.f - 2.f * (expf(c * __uint_as_float(T51) - Mv) * gZ);

  float* pr_o = out + 1;
  float* zi_o = out + 1 + 2097152;
  float* zc_o = out + 1 + 4194304;
#pragma unroll
  for (int g = 0; g < 8; g++) {
    float4 pr4, zi4, zc4;
    float e0 = __uint_as_float(u[g * 4 + 0]) * gZ;
    float e1 = __uint_as_float(u[g * 4 + 1]) * gZ;
    float e2 = __uint_as_float(u[g * 4 + 2]) * gZ;
    float e3 = __uint_as_float(u[g * 4 + 3]) * gZ;
    pr4 = make_float4(e0, e1, e2, e3);
    zi4 = make_float4(2.f * e0 - 1.f, 2.f * e1 - 1.f, 2.f * e2 - 1.f,
                      2.f * e3 - 1.f);
    zc4 = make_float4(zi4.x + shift, zi4.y + shift, zi4.z + shift,
                      zi4.w + shift);
    const size_t o = rb + g * 256 + lane * 4;
    *(float4*)(pr_o + o) = pr4;
    *(float4*)(zi_o + o) = zi4;
    *(float4*)(zc_o + o) = zc4;
  }
}

__global__ void loss_reduce_kernel(const float* __restrict__ lp,
                                   float* __restrict__ out) {
  const int tid = threadIdx.x;
  float s = 0.f;
  for (int i = tid; i < 1024; i += 256) s += lp[i];
  __shared__ float sf[4];
  float v = s;
#pragma unroll
  for (int o = 32; o; o >>= 1) v += __shfl_down(v, o, 64);
  if ((tid & 63) == 0) sf[tid >> 6] = v;
  __syncthreads();
  if (tid == 0) out[0] = (sf[0] + sf[1] + sf[2] + sf[3]) * (1.f / (1024.f * 2048.f));
}

// -------------------------------------------------------------- launch -----

extern "C" void kernel_launch(void* const* d_in, const int* in_sizes, int n_in,
                              void* d_out, int out_size, void* d_ws, size_t ws_size,
                              hipStream_t stream) {
  (void)in_sizes; (void)n_in; (void)out_size; (void)ws_size;
  const float* inputs  = (const float*)d_in[0];  // [1024][4096]
  const float* targets = (const float*)d_in[1];  // [1024][2048]
  const float* w_enc   = (const float*)d_in[2];  // [4096][4096]
  const float* b_enc   = (const float*)d_in[3];  // [4096]
  const float* w_dec   = (const float*)d_in[4];  // [4096][2048]
  const float* b_dec   = (const float*)d_in[5];  // [2048]
  float* out = (float*)d_out;

  // 64 MB workspace layout (R2..R7-proven footprint):
  char* ws = (char*)d_ws;
  u16* A16 = (u16*)ws;                      //  8 MB  [0, 8M)   dead post-GEMM1
  u16* W1T = (u16*)(ws + (8u << 20));       // 32 MB  [8M, 40M) dead post-GEMM1
  u16* W2T = (u16*)(ws + (40u << 20));      // 16 MB  [40M,56M)
  u16* H16 = (u16*)(ws + (56u << 20));      //  8 MB  [56M,64M)
  float* lgts  = (float*)(ws + (8u << 20)); // 4x8 MB overlays dead W1T
  float* lossp = (float*)ws;                //  4 KB  overlays dead A16

  // fused prep: cast inputs + transpose-cast both weights (one dispatch)
  prep_kernel<<<16384, 256, 0, stream>>>(inputs, w_enc, w_dec, A16, W1T, W2T);

  // hidden = leaky_relu(A @ W1 + b_enc) -> bf16   (grid 256, 1 block/CU)
  gemm2ph_kernel<1><<<dim3(32, 8), 256, 0, stream>>>(
      A16, W1T, b_enc, (void*)H16, 1024, 4096, 4096, 4096);
  // logits partials = hidden @ W2, K-split 4      (grid 512, 2 blocks/CU)
  gemm2ph_kernel<0><<<dim3(16, 8, 4), 256, 0, stream>>>(
      H16, W2T, nullptr, (void*)lgts, 1024, 2048, 4096, 1024);

  const float* q0 = lgts;
  const float* q1 = lgts + (size_t)2 * 1024 * 1024;
  const float* q2 = lgts + (size_t)4 * 1024 * 1024;
  const float* q3 = lgts + (size_t)6 * 1024 * 1024;
  epilogue_wave_kernel<<<256, 256, 0, stream>>>(q0, q1, q2, q3, b_dec,
                                                targets, out, lossp);
  loss_reduce_kernel<<<1, 256, 0, stream>>>(lossp, out);
}